// Round 9
// baseline (305.182 us; speedup 1.0000x reference)
//
#include <hip/hip_runtime.h>
#include <hip/hip_bf16.h>

typedef __hip_bfloat16 bf16_t;
typedef __bf16 bf16x8 __attribute__((ext_vector_type(8)));
typedef float f32x4 __attribute__((ext_vector_type(4)));

#define LQ 512
#define LK 4096
#define BATCH 4
#define DMODEL 512
#define NHEAD 8
#define HEADDIM 64
#define DFF 2048
#define LN_EPS 1e-5f

// padded strides: 64B-aligned rows (no line straddle), rotate 64B/row mod 4KB
#define KSTR 2080   // elements per key in k_buf: 4160B/key
#define VSTR 4128   // elements per (b,c) row in vT: 8256B/row

__device__ inline float tofl(float x) { return x; }
__device__ inline float tofl(bf16_t x) { return __bfloat162float(x); }
__device__ inline void stfl(float* p, float v) { *p = v; }
__device__ inline void stfl(bf16_t* p, float v) { *p = __float2bfloat16(v); }

// async global->LDS 16B copy: LDS dest = wave-uniform base + lane*16
__device__ __forceinline__ void gld_lds16(const bf16_t* g, void* lds_base) {
    __builtin_amdgcn_global_load_lds(
        (const __attribute__((address_space(1))) uint32_t*)g,
        (__attribute__((address_space(3))) uint32_t*)lds_base, 16, 0, 0);
}

// ---------- prep: Wq/Wk/Wv/Wo + W1 conversions ----------
__global__ void prep_kernel(const float* __restrict__ s0, const float* __restrict__ s1,
                            const float* __restrict__ s2, const float* __restrict__ s3,
                            const float* __restrict__ s4,
                            bf16_t* __restrict__ wqkvo, bf16_t* __restrict__ w1bf) {
    int t = blockIdx.x * 256 + threadIdx.x;
    int which = t >> 16;            // 0..7, 262144 elements each
    int idx = (t & 65535) * 4;
    const float* s; bf16_t* d;
    if (which < 4) {
        s = (which == 0 ? s0 : which == 1 ? s1 : which == 2 ? s2 : s3);
        d = wqkvo + (size_t)which * 262144;
    } else {
        s = s4 + (size_t)(which - 4) * 262144;
        d = w1bf + (size_t)(which - 4) * 262144;
    }
    float4 v = *(const float4*)(s + idx);
    d[idx + 0] = __float2bfloat16(v.x);
    d[idx + 1] = __float2bfloat16(v.y);
    d[idx + 2] = __float2bfloat16(v.z);
    d[idx + 3] = __float2bfloat16(v.w);
}

// ---------- W2 conversion (runs after transpose; lands in dead v_buf region) ----------
__global__ void conv_w2(const float* __restrict__ s, bf16_t* __restrict__ d) {
    int i = (blockIdx.x * 256 + threadIdx.x) * 4;
    float4 v = *(const float4*)(s + i);
    d[i + 0] = __float2bfloat16(v.x);
    d[i + 1] = __float2bfloat16(v.y);
    d[i + 2] = __float2bfloat16(v.z);
    d[i + 3] = __float2bfloat16(v.w);
}

// ---------- LayerNorm (generic, templated) ----------
template <typename TOUT, bool DUAL>
__global__ void ln_kernel(const float* __restrict__ in, const float* __restrict__ w,
                          const float* __restrict__ b, TOUT* __restrict__ out1,
                          float* __restrict__ out2) {
    __shared__ float red[256];
    const int row = blockIdx.x;
    const int tid = threadIdx.x;
    const float* x = in + (size_t)row * DMODEL;
    float v0 = x[tid];
    float v1 = x[tid + 256];

    red[tid] = v0 + v1;
    __syncthreads();
    for (int s = 128; s > 0; s >>= 1) { if (tid < s) red[tid] += red[tid + s]; __syncthreads(); }
    float mu = red[0] * (1.0f / DMODEL);
    __syncthreads();

    float d0 = v0 - mu, d1 = v1 - mu;
    red[tid] = d0 * d0 + d1 * d1;
    __syncthreads();
    for (int s = 128; s > 0; s >>= 1) { if (tid < s) red[tid] += red[tid + s]; __syncthreads(); }
    float inv = rsqrtf(red[0] * (1.0f / DMODEL) + LN_EPS);

    float r0 = d0 * inv * w[tid] + b[tid];
    float r1 = d1 * inv * w[tid + 256] + b[tid + 256];
    TOUT* o = out1 + (size_t)row * DMODEL;
    stfl(&o[tid], r0);
    stfl(&o[tid + 256], r1);
    if (DUAL) {
        float* o2 = out2 + (size_t)row * DMODEL;
        o2[tid] = r0;
        o2[tid + 256] = r1;
    }
}

// ---------- fused LN1 + LN2 ----------
__global__ void ln12_kernel(const float* __restrict__ tgt, const float* __restrict__ memory,
                            const float* __restrict__ w1, const float* __restrict__ b1,
                            const float* __restrict__ w2, const float* __restrict__ b2,
                            bf16_t* __restrict__ t_bf, float* __restrict__ t_f32,
                            bf16_t* __restrict__ m_buf) {
    __shared__ float red[256];
    const int row = blockIdx.x;
    const int tid = threadIdx.x;
    const float* in; const float* w; const float* b;
    bf16_t* o1; float* o2; bool dual;
    if (row < 2048) {
        in = tgt + (size_t)row * DMODEL; w = w1; b = b1;
        o1 = t_bf + (size_t)row * DMODEL; o2 = t_f32 + (size_t)row * DMODEL; dual = true;
    } else {
        int r2 = row - 2048;
        in = memory + (size_t)r2 * DMODEL; w = w2; b = b2;
        o1 = m_buf + (size_t)r2 * DMODEL; o2 = nullptr; dual = false;
    }
    float v0 = in[tid];
    float v1 = in[tid + 256];
    red[tid] = v0 + v1;
    __syncthreads();
    for (int s = 128; s > 0; s >>= 1) { if (tid < s) red[tid] += red[tid + s]; __syncthreads(); }
    float mu = red[0] * (1.0f / DMODEL);
    __syncthreads();
    float d0 = v0 - mu, d1 = v1 - mu;
    red[tid] = d0 * d0 + d1 * d1;
    __syncthreads();
    for (int s = 128; s > 0; s >>= 1) { if (tid < s) red[tid] += red[tid + s]; __syncthreads(); }
    float inv = rsqrtf(red[0] * (1.0f / DMODEL) + LN_EPS);
    float r0 = d0 * inv * w[tid] + b[tid];
    float r1 = d1 * inv * w[tid + 256] + b[tid + 256];
    o1[tid] = __float2bfloat16(r0);
    o1[tid + 256] = __float2bfloat16(r1);
    if (dual) {
        o2[tid] = r0;
        o2[tid + 256] = r1;
    }
}

// ---------- MFMA GEMM, 64x64 tile: max grid-fill for small GEMMs ----------
// R8 proved: doubling blocks on these latency-bound GEMMs beats tile
// efficiency. Same staging/swizzle math as the 128-tile original.
template <typename TC, bool RELU, bool RESID>
__global__ __launch_bounds__(256) void gemm64(
        const bf16_t* __restrict__ A, const bf16_t* __restrict__ B,
        const float* __restrict__ bias, const float* __restrict__ resid,
        TC* __restrict__ C, int M, int N, int K) {
    __shared__ uint4 As4[512];           // 64 rows x 8 chunks
    __shared__ uint4 Bs4[512];

    const int tid = threadIdx.x;
    const int lane = tid & 63;
    const int wave = tid >> 6;
    const int row16 = lane & 15;
    const int quad = lane >> 4;
    const int n0 = blockIdx.x * 64;
    const int m0 = blockIdx.y * 64;

    const int wy = wave >> 1;            // 0/1
    const int wx = wave & 1;             // 0/1
    const int m_base = wy * 32;
    const int n_base = wx * 32;

    const int rr = lane >> 3;
    const int kc = (lane & 7) ^ rr;
    const int kx = row16 & 7;

    const bf16_t* AsE = (const bf16_t*)As4;
    const bf16_t* BsE = (const bf16_t*)Bs4;

    f32x4 acc[2][2] = {};

    for (int k0 = 0; k0 < K; k0 += 64) {
#pragma unroll
        for (int it = 0; it < 2; it++) {
            int issue = it * 4 + wave;
            int r = issue * 8 + rr;
            gld_lds16(A + (size_t)(m0 + r) * K + k0 + kc * 8, &As4[issue * 64]);
        }
#pragma unroll
        for (int it = 0; it < 2; it++) {
            int issue = it * 4 + wave;
            int r = issue * 8 + rr;
            gld_lds16(B + (size_t)(n0 + r) * K + k0 + kc * 8, &Bs4[issue * 64]);
        }
        __syncthreads();
#pragma unroll
        for (int s = 0; s < 2; s++) {
            const int kq = s * 4 + quad;
            const int kcs = (kq ^ kx) * 8;
            bf16x8 af[2], bfr[2];
#pragma unroll
            for (int i = 0; i < 2; i++)
                af[i] = *(const bf16x8*)&AsE[(m_base + i * 16 + row16) * 64 + kcs];
#pragma unroll
            for (int j = 0; j < 2; j++)
                bfr[j] = *(const bf16x8*)&BsE[(n_base + j * 16 + row16) * 64 + kcs];
#pragma unroll
            for (int i = 0; i < 2; i++)
#pragma unroll
                for (int j = 0; j < 2; j++)
                    acc[i][j] = __builtin_amdgcn_mfma_f32_16x16x32_bf16(af[i], bfr[j], acc[i][j], 0, 0, 0);
        }
        __syncthreads();
    }

#pragma unroll
    for (int i = 0; i < 2; i++) {
#pragma unroll
        for (int j = 0; j < 2; j++) {
            int col = n0 + n_base + j * 16 + row16;
            float bsv = bias[col];
#pragma unroll
            for (int r = 0; r < 4; r++) {
                int row = m0 + m_base + i * 16 + quad * 4 + r;
                float val = acc[i][j][r] + bsv;
                if (RESID) val += resid[(size_t)row * N + col];
                if (RELU) val = fmaxf(val, 0.0f);
                stfl(&C[(size_t)row * N + col], val);
            }
        }
    }
}

// ---------- fused K+V projection, 64x64 tiles, co-running via blockIdx.z ----------
// R8 lesson applied to the M=16384 pair: 2 x 512-block serial launches ->
// one 2x2048-block launch (up to 16 blk/CU queue depth). z=0: K-weights +
// key-padded epilogue; z=1: V-weights + linear epilogue. Uniform branch.
__global__ __launch_bounds__(256) void gemm64_kv(
        const bf16_t* __restrict__ A, const bf16_t* __restrict__ BK,
        const bf16_t* __restrict__ BV, const float* __restrict__ biask,
        const float* __restrict__ biasv, bf16_t* __restrict__ CK,
        bf16_t* __restrict__ CV, int M, int N, int K) {
    __shared__ uint4 As4[512];
    __shared__ uint4 Bs4[512];

    const bool isV = blockIdx.z != 0;
    const bf16_t* B = isV ? BV : BK;
    const float* bias = isV ? biasv : biask;

    const int tid = threadIdx.x;
    const int lane = tid & 63;
    const int wave = tid >> 6;
    const int row16 = lane & 15;
    const int quad = lane >> 4;
    const int n0 = blockIdx.x * 64;
    const int m0 = blockIdx.y * 64;

    const int wy = wave >> 1;
    const int wx = wave & 1;
    const int m_base = wy * 32;
    const int n_base = wx * 32;

    const int rr = lane >> 3;
    const int kc = (lane & 7) ^ rr;
    const int kx = row16 & 7;

    const bf16_t* AsE = (const bf16_t*)As4;
    const bf16_t* BsE = (const bf16_t*)Bs4;

    f32x4 acc[2][2] = {};

    for (int k0 = 0; k0 < K; k0 += 64) {
#pragma unroll
        for (int it = 0; it < 2; it++) {
            int issue = it * 4 + wave;
            int r = issue * 8 + rr;
            gld_lds16(A + (size_t)(m0 + r) * K + k0 + kc * 8, &As4[issue * 64]);
        }
#pragma unroll
        for (int it = 0; it < 2; it++) {
            int issue = it * 4 + wave;
            int r = issue * 8 + rr;
            gld_lds16(B + (size_t)(n0 + r) * K + k0 + kc * 8, &Bs4[issue * 64]);
        }
        __syncthreads();
#pragma unroll
        for (int s = 0; s < 2; s++) {
            const int kq = s * 4 + quad;
            const int kcs = (kq ^ kx) * 8;
            bf16x8 af[2], bfr[2];
#pragma unroll
            for (int i = 0; i < 2; i++)
                af[i] = *(const bf16x8*)&AsE[(m_base + i * 16 + row16) * 64 + kcs];
#pragma unroll
            for (int j = 0; j < 2; j++)
                bfr[j] = *(const bf16x8*)&BsE[(n_base + j * 16 + row16) * 64 + kcs];
#pragma unroll
            for (int i = 0; i < 2; i++)
#pragma unroll
                for (int j = 0; j < 2; j++)
                    acc[i][j] = __builtin_amdgcn_mfma_f32_16x16x32_bf16(af[i], bfr[j], acc[i][j], 0, 0, 0);
        }
        __syncthreads();
    }

#pragma unroll
    for (int i = 0; i < 2; i++) {
#pragma unroll
        for (int j = 0; j < 2; j++) {
            int col = n0 + n_base + j * 16 + row16;
            float bsv = bias[col];
#pragma unroll
            for (int r = 0; r < 4; r++) {
                int row = m0 + m_base + i * 16 + quad * 4 + r;
                float val = acc[i][j][r] + bsv;
                if (isV) {
                    CV[(size_t)row * N + col] = __float2bfloat16(val);
                } else {
                    CK[(size_t)(row >> 2) * KSTR + (size_t)(row & 3) * 512 + col] =
                        __float2bfloat16(val);
                }
            }
        }
    }
}

// ---------- transpose: in[(key*4+b)*512 + c] -> out[(b*512+c)*VSTR + key] ----------
__global__ __launch_bounds__(256) void transpose_kv(const bf16_t* __restrict__ kb,
                                                    bf16_t* __restrict__ kT) {
    __shared__ bf16_t tile[64][80];
    const int kt = blockIdx.x * 64;
    const int ct = blockIdx.y * 64;
    const int b  = blockIdx.z;
    const int t = threadIdx.x;
    {
        int kl = t >> 2, cl = (t & 3) * 16;
        const bf16_t* src = kb + ((size_t)(kt + kl) * 4 + b) * 512 + ct + cl;
        *(uint4*)&tile[kl][cl]     = *(const uint4*)src;
        *(uint4*)&tile[kl][cl + 8] = *(const uint4*)(src + 8);
    }
    __syncthreads();
    {
        int cl2 = t >> 2, ks = (t & 3) * 16;
        __attribute__((aligned(16))) bf16_t vals[16];
#pragma unroll
        for (int j = 0; j < 16; j++) vals[j] = tile[ks + j][cl2];
        bf16_t* dst = kT + ((size_t)b * 512 + ct + cl2) * VSTR + kt + ks;
        *(uint4*)dst       = *(const uint4*)&vals[0];
        *(uint4*)(dst + 8) = *(const uint4*)&vals[8];
    }
}

// ======== attn helpers: statically-indexed load groups (rule #20) ========
__device__ __forceinline__ void qk_issue(const bf16_t* kb_base, int us, int g,
                                         int row16, bf16x8 (&b0)[8], bf16x8 (&b1)[8]) {
#pragma unroll
    for (int j = 0; j < 8; ++j) {
        int key = us + (g * 8 + j) * 16 + row16;
        int key_eff = key > 4095 ? 4095 : key;
        const bf16_t* kr = kb_base + (size_t)key_eff * KSTR;
        b0[j] = *(const bf16x8*)kr;
        b1[j] = *(const bf16x8*)(kr + 32);
    }
}

__device__ __forceinline__ void qk_compute(int g, bf16x8 (&b0)[8], bf16x8 (&b1)[8],
        const bf16x8 aq0, const bf16x8 aq1, float (&l)[4], bf16_t* PsH,
        int row16, int quad, const int (&sq)[4], const int (&eq)[4], int us) {
    __builtin_amdgcn_s_setprio(1);
#pragma unroll
    for (int j = 0; j < 8; ++j) {
        int it = g * 8 + j;
        f32x4 acc = {};
        acc = __builtin_amdgcn_mfma_f32_16x16x32_bf16(aq0, b0[j], acc, 0, 0, 0);
        acc = __builtin_amdgcn_mfma_f32_16x16x32_bf16(aq1, b1[j], acc, 0, 0, 0);
        int key = us + it * 16 + row16;
#pragma unroll
        for (int r = 0; r < 4; r++) {
            int ql = quad * 4 + r;
            bool valid = (key >= sq[r]) && (key < eq[r]);
            float p = valid ? __expf(0.125f * acc[r]) : 0.0f;
            l[r] += p;
            if (ql < 8) PsH[ql * 904 + it * 16 + row16] = __float2bfloat16(p);
        }
    }
    __builtin_amdgcn_s_setprio(0);
}

__device__ __forceinline__ void pv_issue(const bf16_t* vbase, int g, int row16, int quad,
                                         bf16x8 (&vb)[4][4]) {
#pragma unroll
    for (int j = 0; j < 4; ++j) {
        int it = g * 4 + j;
#pragma unroll
        for (int nt = 0; nt < 4; ++nt)
            vb[j][nt] = *(const bf16x8*)(vbase + (size_t)(nt * 16 + row16) * VSTR
                                         + it * 32 + quad * 8);
    }
}

__device__ __forceinline__ void pv_compute(int g, bf16x8 (&vb)[4][4], const bf16_t* PsH,
        const bf16_t* Zrow, int row16, int quad, f32x4 (&o)[4]) {
    __builtin_amdgcn_s_setprio(1);
#pragma unroll
    for (int j = 0; j < 4; ++j) {
        int it = g * 4 + j;
        const bf16_t* ap_src = (row16 < 8) ? &PsH[row16 * 904 + it * 32 + quad * 8]
                                           : &Zrow[0];
        bf16x8 ap = *(const bf16x8*)ap_src;
#pragma unroll
        for (int nt = 0; nt < 4; ++nt)
            o[nt] = __builtin_amdgcn_mfma_f32_16x16x32_bf16(ap, vb[j][nt], o[nt], 0, 0, 0);
    }
    __builtin_amdgcn_s_setprio(0);
}

// ---------- MFMA flash attention v8 (proven 51us): 2-deep pipeline + setprio ----------
__global__ __launch_bounds__(512, 1) void attn_mfma(
        const bf16_t* __restrict__ qb,   // [2048,512] rows (q*4+b)
        const bf16_t* __restrict__ kb,   // [4096][KSTR] key-padded
        const bf16_t* __restrict__ vT,   // [4][512][VSTR]
        bf16_t* __restrict__ ctx,        // [2048,512]
        float* __restrict__ attn_out) {  // [4][512][4096], written in full here
    extern __shared__ char smem[];
    bf16_t* Ps   = (bf16_t*)smem;                         // [8 heads][8 q][904]
    bf16_t* Qs   = (bf16_t*)(smem + 115712);              // [8 q][520]
    bf16_t* Zrow = (bf16_t*)(smem + 115712 + 8320);       // [904]
    float*  Ls   = (float*)(smem + 115712 + 8320 + 1808); // [8 heads][8 q] 1/l

    const int blk = blockIdx.x;
    const int b  = (blk & 7) >> 1;                 // batch locked to XCD pair
    const int qt = ((blk >> 3) << 1) | (blk & 1);  // 0..63
    const int q0 = qt * 8;
    const int tid = threadIdx.x;
    const int lane = tid & 63;
    const int h = tid >> 6;          // wave = head 0..7
    const int hoffg = h * HEADDIM;
    const int row16 = lane & 15;
    const int quad = lane >> 4;

    int us; { int s = q0 * 8, e = s + 827; if (e > 4095) s = 3268; us = s; }
    int sq[4], eq[4];
#pragma unroll
    for (int r = 0; r < 4; r++) {
        int ql = quad * 4 + r;
        if (ql < 8) {
            int s = (q0 + ql) * 8, e = s + 827;
            if (e > 4095) { s = 3268; e = 4096; }
            sq[r] = s; eq[r] = e;
        } else { sq[r] = 0; eq[r] = 0; }
    }

    {   // stage Q: 8 rows x 512 cols (16B per thread)
        int r = tid >> 6, coff = (tid & 63) * 8;
        *(uint4*)&Qs[r * 520 + coff] =
            *(const uint4*)(qb + ((size_t)(q0 + r) * 4 + b) * 512 + coff);
        if (tid < 113) { uint4 z = {0, 0, 0, 0}; *(uint4*)&Zrow[tid * 8] = z; }
    }
    __syncthreads();

    const bf16_t* q0p = (row16 < 8) ? &Qs[row16 * 520 + hoffg + quad * 8] : &Zrow[0];
    const bf16_t* q1p = (row16 < 8) ? &Qs[row16 * 520 + hoffg + 32 + quad * 8] : &Zrow[8];
    const bf16x8 aq0 = *(const bf16x8*)q0p;
    const bf16x8 aq1 = *(const bf16x8*)q1p;

    bf16_t* PsH = Ps + h * 8 * 904;
    const bf16_t* kb_base = kb + b * 512 + hoffg + quad * 8;

    // ---- QK: 7 groups of 8, 2-deep ping-pong register pipeline ----
    bf16x8 ka0[8], ka1[8], kc0[8], kc1[8];
    float l[4] = {0.f, 0.f, 0.f, 0.f};
    qk_issue(kb_base, us, 0, row16, ka0, ka1);
    for (int gg = 0; gg < 3; ++gg) {
        qk_issue(kb_base, us, 2 * gg + 1, row16, kc0, kc1);
        qk_compute(2 * gg, ka0, ka1, aq0, aq1, l, PsH, row16, quad, sq, eq, us);
        qk_issue(kb_base, us, 2 * gg + 2, row16, ka0, ka1);
        qk_compute(2 * gg + 1, kc0, kc1, aq0, aq1, l, PsH, row16, quad, sq, eq, us);
    }
    // PV group-0 loads issue before the final QK compute + the shuffle reduce
    bf16x8 va[4][4], vb_[4][4];
    const bf16_t* vbase = vT + (size_t)(b * 512 + hoffg) * VSTR + us;
    pv_issue(vbase, 0, row16, quad, va);
    qk_compute(6, ka0, ka1, aq0, aq1, l, PsH, row16, quad, sq, eq, us);

#pragma unroll
    for (int off = 1; off < 16; off <<= 1) {
#pragma unroll
        for (int r = 0; r < 4; r++) l[r] += __shfl_xor(l[r], off, 64);
    }
    float linv[4];
#pragma unroll
    for (int r = 0; r < 4; r++) linv[r] = 1.0f / l[r];
    if (row16 == 0) {
#pragma unroll
        for (int r = 0; r < 4; r++) {
            int ql = quad * 4 + r;
            if (ql < 8) Ls[h * 8 + ql] = linv[r];
        }
    }

    // ---- PV: 7 groups of 4, 2-deep ping-pong (no barrier: own-head Ps) ----
    f32x4 o[4] = {};
    for (int gg = 0; gg < 3; ++gg) {
        pv_issue(vbase, 2 * gg + 1, row16, quad, vb_);
        pv_compute(2 * gg, va, PsH, Zrow, row16, quad, o);
        pv_issue(vbase, 2 * gg + 2, row16, quad, va);
        pv_compute(2 * gg + 1, vb_, PsH, Zrow, row16, quad, o);
    }
    pv_compute(6, va, PsH, Zrow, row16, quad, o);

    __syncthreads();   // all heads' Ps + Ls final -> mean may read

    // ---- attn_out head-mean: full-row stores (zeros outside window) ----
    {
        int qq = h;                    // wave qq owns q-row q0+qq entirely
        float ls[8];
#pragma unroll
        for (int hh = 0; hh < 8; ++hh) ls[hh] = 0.125f * Ls[hh * 8 + qq];
        float* rowp = attn_out + ((size_t)b * LQ + q0 + qq) * LK;
        const bf16_t* ps = Ps + qq * 904;
        for (int it = 0; it < 16; ++it) {
            int c4 = (it * 64 + lane) * 4;          // first col of this float4
            float4 v = {0.f, 0.f, 0.f, 0.f};
            int off = c4 - us;                      // Ps col of element 0
            if (off >= -3 && off < 896) {
#pragma unroll
                for (int e = 0; e < 4; ++e) {
                    int pc = off + e;
                    float s = 0.f;
                    if (pc >= 0 && pc < 896) {
#pragma unroll
                        for (int hh = 0; hh < 8; ++hh)
                            s += ls[hh] * tofl(ps[hh * 8 * 904 + pc]);
                    }
                    (&v.x)[e] = s;
                }
            }
            *(float4*)(rowp + c4) = v;
        }
    }

    // ---- ctx write (own head, no cross-wave combine) ----
#pragma unroll
    for (int nt = 0; nt < 4; nt++) {
#pragma unroll
        for (int r = 0; r < 4; r++) {
            int ql = quad * 4 + r;
            if (ql < 8) {
                ctx[((size_t)(q0 + ql) * 4 + b) * 512 + hoffg + nt * 16 + row16] =
                    __float2bfloat16(o[nt][r] * linv[r]);
            }
        }
    }
}

extern "C" void kernel_launch(void* const* d_in, const int* in_sizes, int n_in,
                              void* d_out, int out_size, void* d_ws, size_t ws_size,
                              hipStream_t stream) {
    const float* tgt    = (const float*)d_in[0];
    const float* memory = (const float*)d_in[1];
    const float* Wq = (const float*)d_in[2];
    const float* bq = (const float*)d_in[3];
    const float* Wk = (const float*)d_in[4];
    const float* bk = (const float*)d_in[5];
    const float* Wv = (const float*)d_in[6];
    const float* bv = (const float*)d_in[7];
    const float* Wo = (const float*)d_in[8];
    const float* bo = (const float*)d_in[9];
    const float* W1 = (const float*)d_in[10];
    const float* b1 = (const float*)d_in[11];
    const float* W2 = (const float*)d_in[12];
    const float* b2 = (const float*)d_in[13];
    const float* ln1w = (const float*)d_in[14];
    const float* ln1b = (const float*)d_in[15];
    const float* ln2w = (const float*)d_in[16];
    const float* ln2b = (const float*)d_in[17];
    const float* ln3w = (const float*)d_in[18];
    const float* ln3b = (const float*)d_in[19];
    const float* ln4w = (const float*)d_in[20];
    const float* ln4b = (const float*)d_in[21];

    const size_t M1 = (size_t)LQ * BATCH;      // 2048
    const size_t M2 = (size_t)LK * BATCH;      // 16384
    const size_t SZ1 = M1 * DMODEL;

    // ---- workspace map (64 MiB, lifetime-aliased; padded K/vT) ----
    char* wsb = (char*)d_ws;
    const size_t MB = 1 << 20;
    bf16_t* m_buf   = (bf16_t*)(wsb + 0 * MB);   // [2->5], 16MB
    bf16_t* vT_buf  = (bf16_t*)(wsb + 0 * MB);   // [6->7], 16.13MB (m dead)
    bf16_t* h_buf   = (bf16_t*)(wsb + 0 * MB);   // [10->11], 8MB (vT dead)
    bf16_t* k_buf   = (bf16_t*)(wsb + 17 * MB);  // [4->7], 16.25MB padded
    float*  xres    = (float*)(wsb + 17 * MB);   // [8->9], 4MB (k dead)
    float*  xln_f   = (float*)(wsb + 21 * MB);   // [9->11], 4MB
    float*  x2_buf  = (float*)(wsb + 25 * MB);   // [11->12], 4MB
    bf16_t* W2_bf   = (bf16_t*)(wsb + 34 * MB);  // [6.5->11], 2MB (v region head, v dead)
    bf16_t* v_buf   = (bf16_t*)(wsb + 34 * MB);  // [5->6], 16MB
    bf16_t* t_bf    = (bf16_t*)(wsb + 50 * MB);  // [2->3], 2MB
    bf16_t* xln_bf  = (bf16_t*)(wsb + 50 * MB);  // [9->10], 2MB (t_bf dead)
    float*  t_f32   = (float*)(wsb + 52 * MB);   // [2->8], 4MB
    bf16_t* q_bf    = (bf16_t*)(wsb + 56 * MB);  // [3->7], 2MB
    bf16_t* ctx_buf = (bf16_t*)(wsb + 58 * MB);  // [7->8], 2MB
    bf16_t* wqkvo   = (bf16_t*)(wsb + 60 * MB);  // [1->8], 2MB
    bf16_t* W1_bf   = (bf16_t*)(wsb + 62 * MB);  // [1->10], 2MB

    bf16_t* Wq_bf = wqkvo;
    bf16_t* Wk_bf = wqkvo + 262144;
    bf16_t* Wv_bf = wqkvo + 2 * 262144;
    bf16_t* Wo_bf = wqkvo + 3 * 262144;

    float* out_x    = (float*)d_out;
    float* out_attn = out_x + SZ1;

    // 1. qkvo + W1 conversions (attn_out fully written by attn itself)
    prep_kernel<<<dim3(2048), dim3(256), 0, stream>>>(
        Wq, Wk, Wv, Wo, W1, wqkvo, W1_bf);

    // 2. LN1 (dual) + LN2 fused
    ln12_kernel<<<dim3(M1 + M2), dim3(256), 0, stream>>>(
        tgt, memory, ln1w, ln1b, ln2w, ln2b, t_bf, t_f32, m_buf);

    // 3. Q projection (64x64 tiles: 256 blocks)
    gemm64<bf16_t, false, false><<<dim3(8, 32), dim3(256), 0, stream>>>(
        t_bf, Wq_bf, bq, nullptr, q_bf, M1, DMODEL, DMODEL);

    // 4. K+V projections: ONE launch, 2x2048 blocks co-running
    gemm64_kv<<<dim3(8, 256, 2), dim3(256), 0, stream>>>(
        m_buf, Wk_bf, Wv_bf, bk, bv, k_buf, v_buf, M2, DMODEL, DMODEL);

    // 6. V transpose to padded [b][d][VSTR] (m_buf dead -> vT region)
    transpose_kv<<<dim3(64, 8, 4), dim3(256), 0, stream>>>(v_buf, vT_buf);

    // 6.5 W2 conversion into dead v_buf head
    conv_w2<<<dim3(1024), dim3(256), 0, stream>>>(W2, W2_bf);

    // 7. attention: 256 blocks x 8 waves (= 8 heads), 126KB dynamic LDS
    const int attn_lds = 115712 + 8320 + 1808 + 256;   // 126096 B
    hipFuncSetAttribute((const void*)attn_mfma,
                        hipFuncAttributeMaxDynamicSharedMemorySize, attn_lds);
    attn_mfma<<<dim3(256), dim3(512), attn_lds, stream>>>(
        q_bf, k_buf, vT_buf, ctx_buf, out_attn);

    // 8. out proj + residual(t) -> xres (64x64 tiles, 256 blocks)
    gemm64<float, false, true><<<dim3(8, 32), dim3(256), 0, stream>>>(
        ctx_buf, Wo_bf, bo, t_f32, xres, M1, DMODEL, DMODEL);

    // 9. LN3 (dual)
    ln_kernel<bf16_t, true><<<dim3(M1), dim3(256), 0, stream>>>(xres, ln3w, ln3b, xln_bf, xln_f);

    // 10. FF1 (relu): 64x64 tiles -> 1024 blocks (was 256 at 1 blk/CU)
    gemm64<bf16_t, true, false><<<dim3(32, 32), dim3(256), 0, stream>>>(
        xln_bf, W1_bf, b1, nullptr, h_buf, M1, DFF, DMODEL);

    // 11. FF2 + residual(xln) (64x64 tiles, 256 blocks)
    gemm64<float, false, true><<<dim3(8, 32), dim3(256), 0, stream>>>(
        h_buf, W2_bf, b2, xln_f, x2_buf, M1, DMODEL, DFF);

    // 12. LN4 -> fp32 out
    ln_kernel<float, false><<<dim3(M1), dim3(256), 0, stream>>>(x2_buf, ln4w, ln4b, out_x, nullptr);
}

// Round 11
// 287.509 us; speedup vs baseline: 1.0615x; 1.0615x over previous
//
#include <hip/hip_runtime.h>
#include <hip/hip_bf16.h>

typedef __hip_bfloat16 bf16_t;
typedef __bf16 bf16x8 __attribute__((ext_vector_type(8)));
typedef float f32x4 __attribute__((ext_vector_type(4)));

#define LQ 512
#define LK 4096
#define BATCH 4
#define DMODEL 512
#define NHEAD 8
#define HEADDIM 64
#define DFF 2048
#define LN_EPS 1e-5f

// padded strides: 64B-aligned rows (no line straddle), rotate 64B/row mod 4KB
#define KSTR 2080   // elements per key in k_buf: 4160B/key
#define VSTR 4128   // elements per (b,c) row in vT: 8256B/row

__device__ inline float tofl(float x) { return x; }
__device__ inline float tofl(bf16_t x) { return __bfloat162float(x); }
__device__ inline void stfl(float* p, float v) { *p = v; }
__device__ inline void stfl(bf16_t* p, float v) { *p = __float2bfloat16(v); }

// async global->LDS 16B copy: LDS dest = wave-uniform base + lane*16
__device__ __forceinline__ void gld_lds16(const bf16_t* g, void* lds_base) {
    __builtin_amdgcn_global_load_lds(
        (const __attribute__((address_space(1))) uint32_t*)g,
        (__attribute__((address_space(3))) uint32_t*)lds_base, 16, 0, 0);
}

// ---------- W2 conversion (runs after transpose; lands in dead v_buf region) ----------
__global__ void conv_w2(const float* __restrict__ s, bf16_t* __restrict__ d) {
    int i = (blockIdx.x * 256 + threadIdx.x) * 4;
    float4 v = *(const float4*)(s + i);
    d[i + 0] = __float2bfloat16(v.x);
    d[i + 1] = __float2bfloat16(v.y);
    d[i + 2] = __float2bfloat16(v.z);
    d[i + 3] = __float2bfloat16(v.w);
}

// ---------- LayerNorm (generic, templated) ----------
template <typename TOUT, bool DUAL>
__global__ void ln_kernel(const float* __restrict__ in, const float* __restrict__ w,
                          const float* __restrict__ b, TOUT* __restrict__ out1,
                          float* __restrict__ out2) {
    __shared__ float red[256];
    const int row = blockIdx.x;
    const int tid = threadIdx.x;
    const float* x = in + (size_t)row * DMODEL;
    float v0 = x[tid];
    float v1 = x[tid + 256];

    red[tid] = v0 + v1;
    __syncthreads();
    for (int s = 128; s > 0; s >>= 1) { if (tid < s) red[tid] += red[tid + s]; __syncthreads(); }
    float mu = red[0] * (1.0f / DMODEL);
    __syncthreads();

    float d0 = v0 - mu, d1 = v1 - mu;
    red[tid] = d0 * d0 + d1 * d1;
    __syncthreads();
    for (int s = 128; s > 0; s >>= 1) { if (tid < s) red[tid] += red[tid + s]; __syncthreads(); }
    float inv = rsqrtf(red[0] * (1.0f / DMODEL) + LN_EPS);

    float r0 = d0 * inv * w[tid] + b[tid];
    float r1 = d1 * inv * w[tid + 256] + b[tid + 256];
    TOUT* o = out1 + (size_t)row * DMODEL;
    stfl(&o[tid], r0);
    stfl(&o[tid + 256], r1);
    if (DUAL) {
        float* o2 = out2 + (size_t)row * DMODEL;
        o2[tid] = r0;
        o2[tid + 256] = r1;
    }
}

// ---------- fused LN1 + LN2 + weight-prep (one leading launch) ----------
// blocks [0,18432): LN rows; [18432,20480): Wq/Wk/Wv/Wo+W1 bf16 conversion.
__global__ void ln12_prep_kernel(const float* __restrict__ tgt, const float* __restrict__ memory,
                                 const float* __restrict__ w1, const float* __restrict__ b1,
                                 const float* __restrict__ w2, const float* __restrict__ b2,
                                 bf16_t* __restrict__ t_bf, float* __restrict__ t_f32,
                                 bf16_t* __restrict__ m_buf,
                                 const float* __restrict__ s0, const float* __restrict__ s1,
                                 const float* __restrict__ s2, const float* __restrict__ s3,
                                 const float* __restrict__ s4,
                                 bf16_t* __restrict__ wqkvo, bf16_t* __restrict__ w1bf) {
    const int row = blockIdx.x;
    const int tid = threadIdx.x;
    if (row >= 18432) {
        // ---- prep path ----
        int t = (row - 18432) * 256 + tid;
        int which = t >> 16;            // 0..7, 262144 elements each
        int idx = (t & 65535) * 4;
        const float* s; bf16_t* d;
        if (which < 4) {
            s = (which == 0 ? s0 : which == 1 ? s1 : which == 2 ? s2 : s3);
            d = wqkvo + (size_t)which * 262144;
        } else {
            s = s4 + (size_t)(which - 4) * 262144;
            d = w1bf + (size_t)(which - 4) * 262144;
        }
        float4 v = *(const float4*)(s + idx);
        d[idx + 0] = __float2bfloat16(v.x);
        d[idx + 1] = __float2bfloat16(v.y);
        d[idx + 2] = __float2bfloat16(v.z);
        d[idx + 3] = __float2bfloat16(v.w);
        return;
    }
    __shared__ float red[256];
    const float* in; const float* w; const float* b;
    bf16_t* o1; float* o2; bool dual;
    if (row < 2048) {
        in = tgt + (size_t)row * DMODEL; w = w1; b = b1;
        o1 = t_bf + (size_t)row * DMODEL; o2 = t_f32 + (size_t)row * DMODEL; dual = true;
    } else {
        int r2 = row - 2048;
        in = memory + (size_t)r2 * DMODEL; w = w2; b = b2;
        o1 = m_buf + (size_t)r2 * DMODEL; o2 = nullptr; dual = false;
    }
    float v0 = in[tid];
    float v1 = in[tid + 256];
    red[tid] = v0 + v1;
    __syncthreads();
    for (int s = 128; s > 0; s >>= 1) { if (tid < s) red[tid] += red[tid + s]; __syncthreads(); }
    float mu = red[0] * (1.0f / DMODEL);
    __syncthreads();
    float d0 = v0 - mu, d1 = v1 - mu;
    red[tid] = d0 * d0 + d1 * d1;
    __syncthreads();
    for (int s = 128; s > 0; s >>= 1) { if (tid < s) red[tid] += red[tid + s]; __syncthreads(); }
    float inv = rsqrtf(red[0] * (1.0f / DMODEL) + LN_EPS);
    float r0 = d0 * inv * w[tid] + b[tid];
    float r1 = d1 * inv * w[tid + 256] + b[tid + 256];
    o1[tid] = __float2bfloat16(r0);
    o1[tid + 256] = __float2bfloat16(r1);
    if (dual) {
        o2[tid] = r0;
        o2[tid + 256] = r1;
    }
}

// ---------- MFMA GEMM, 64x64 tile: for GEMMs with cache-resident operands ----------
// R8/R9 lesson: grid-fill wins when A,B fit L2 (Q/Wo/FF1/FF2); for 16MB-A
// GEMMs (K/V) the extra A re-reads cost more than the occupancy gain.
template <typename TC, bool RELU, bool RESID>
__global__ __launch_bounds__(256) void gemm64(
        const bf16_t* __restrict__ A, const bf16_t* __restrict__ B,
        const float* __restrict__ bias, const float* __restrict__ resid,
        TC* __restrict__ C, int M, int N, int K) {
    __shared__ uint4 As4[512];           // 64 rows x 8 chunks
    __shared__ uint4 Bs4[512];

    const int tid = threadIdx.x;
    const int lane = tid & 63;
    const int wave = tid >> 6;
    const int row16 = lane & 15;
    const int quad = lane >> 4;
    const int n0 = blockIdx.x * 64;
    const int m0 = blockIdx.y * 64;

    const int wy = wave >> 1;            // 0/1
    const int wx = wave & 1;             // 0/1
    const int m_base = wy * 32;
    const int n_base = wx * 32;

    const int rr = lane >> 3;
    const int kc = (lane & 7) ^ rr;
    const int kx = row16 & 7;

    const bf16_t* AsE = (const bf16_t*)As4;
    const bf16_t* BsE = (const bf16_t*)Bs4;

    f32x4 acc[2][2] = {};

    for (int k0 = 0; k0 < K; k0 += 64) {
#pragma unroll
        for (int it = 0; it < 2; it++) {
            int issue = it * 4 + wave;
            int r = issue * 8 + rr;
            gld_lds16(A + (size_t)(m0 + r) * K + k0 + kc * 8, &As4[issue * 64]);
        }
#pragma unroll
        for (int it = 0; it < 2; it++) {
            int issue = it * 4 + wave;
            int r = issue * 8 + rr;
            gld_lds16(B + (size_t)(n0 + r) * K + k0 + kc * 8, &Bs4[issue * 64]);
        }
        __syncthreads();
#pragma unroll
        for (int s = 0; s < 2; s++) {
            const int kq = s * 4 + quad;
            const int kcs = (kq ^ kx) * 8;
            bf16x8 af[2], bfr[2];
#pragma unroll
            for (int i = 0; i < 2; i++)
                af[i] = *(const bf16x8*)&AsE[(m_base + i * 16 + row16) * 64 + kcs];
#pragma unroll
            for (int j = 0; j < 2; j++)
                bfr[j] = *(const bf16x8*)&BsE[(n_base + j * 16 + row16) * 64 + kcs];
#pragma unroll
            for (int i = 0; i < 2; i++)
#pragma unroll
                for (int j = 0; j < 2; j++)
                    acc[i][j] = __builtin_amdgcn_mfma_f32_16x16x32_bf16(af[i], bfr[j], acc[i][j], 0, 0, 0);
        }
        __syncthreads();
    }

#pragma unroll
    for (int i = 0; i < 2; i++) {
#pragma unroll
        for (int j = 0; j < 2; j++) {
            int col = n0 + n_base + j * 16 + row16;
            float bsv = bias[col];
#pragma unroll
            for (int r = 0; r < 4; r++) {
                int row = m0 + m_base + i * 16 + quad * 4 + r;
                float val = acc[i][j][r] + bsv;
                if (RESID) val += resid[(size_t)row * N + col];
                if (RELU) val = fmaxf(val, 0.0f);
                stfl(&C[(size_t)row * N + col], val);
            }
        }
    }
}

// ---------- K+V projections: 128x128 tiles (proven), z-fused single launch ----------
// R9 post-mortem: 64-tiles doubled A re-reads of the 16MB A matrix (+64MB HBM
// per GEMM). This keeps the R8-proven 128^2 per-block structure and only
// merges the two GEMMs into one grid (z=0: K-weights + key-padded epilogue,
// z=1: V-weights + linear epilogue).
__global__ __launch_bounds__(256) void gemm128_kv(
        const bf16_t* __restrict__ A, const bf16_t* __restrict__ BK,
        const bf16_t* __restrict__ BV, const float* __restrict__ biask,
        const float* __restrict__ biasv, bf16_t* __restrict__ CK,
        bf16_t* __restrict__ CV, int M, int N, int K) {
    __shared__ uint4 As4[1024];          // 128 rows x 8 chunks
    __shared__ uint4 Bs4[1024];

    const bool isV = blockIdx.z != 0;
    const bf16_t* B = isV ? BV : BK;
    const float* bias = isV ? biasv : biask;

    const int tid = threadIdx.x;
    const int lane = tid & 63;
    const int wave = tid >> 6;
    const int row16 = lane & 15;
    const int quad = lane >> 4;
    const int n0 = blockIdx.x * 128;
    const int m0 = blockIdx.y * 128;

    const int wy = wave >> 1;
    const int wx = wave & 1;
    const int m_base = wy * 64;
    const int n_base = wx * 64;

    const int rr = lane >> 3;            // 0..7 (row within issue)
    const int kc = (lane & 7) ^ rr;      // swizzled global k-chunk
    const int kx = row16 & 7;            // frag-read deswizzle key

    const bf16_t* AsE = (const bf16_t*)As4;
    const bf16_t* BsE = (const bf16_t*)Bs4;

    f32x4 acc[4][4] = {};

    for (int k0 = 0; k0 < K; k0 += 64) {
#pragma unroll
        for (int it = 0; it < 4; it++) {
            int issue = it * 4 + wave;
            int r = issue * 8 + rr;
            gld_lds16(A + (size_t)(m0 + r) * K + k0 + kc * 8, &As4[issue * 64]);
        }
#pragma unroll
        for (int it = 0; it < 4; it++) {
            int issue = it * 4 + wave;
            int r = issue * 8 + rr;
            gld_lds16(B + (size_t)(n0 + r) * K + k0 + kc * 8, &Bs4[issue * 64]);
        }
        __syncthreads();
#pragma unroll
        for (int s = 0; s < 2; s++) {
            const int kq = s * 4 + quad;
            const int kcs = (kq ^ kx) * 8;
            bf16x8 af[4], bfr[4];
#pragma unroll
            for (int i = 0; i < 4; i++)
                af[i] = *(const bf16x8*)&AsE[(m_base + i * 16 + row16) * 64 + kcs];
#pragma unroll
            for (int j = 0; j < 4; j++)
                bfr[j] = *(const bf16x8*)&BsE[(n_base + j * 16 + row16) * 64 + kcs];
#pragma unroll
            for (int i = 0; i < 4; i++)
#pragma unroll
                for (int j = 0; j < 4; j++)
                    acc[i][j] = __builtin_amdgcn_mfma_f32_16x16x32_bf16(af[i], bfr[j], acc[i][j], 0, 0, 0);
        }
        __syncthreads();
    }

#pragma unroll
    for (int i = 0; i < 4; i++) {
#pragma unroll
        for (int j = 0; j < 4; j++) {
            int col = n0 + n_base + j * 16 + row16;
            float bsv = bias[col];
#pragma unroll
            for (int r = 0; r < 4; r++) {
                int row = m0 + m_base + i * 16 + quad * 4 + r;
                float val = acc[i][j][r] + bsv;
                if (isV) {
                    CV[(size_t)row * N + col] = __float2bfloat16(val);
                } else {
                    CK[(size_t)(row >> 2) * KSTR + (size_t)(row & 3) * 512 + col] =
                        __float2bfloat16(val);
                }
            }
        }
    }
}

// ---------- transpose: in[(key*4+b)*512 + c] -> out[(b*512+c)*VSTR + key] ----------
__global__ __launch_bounds__(256) void transpose_kv(const bf16_t* __restrict__ kb,
                                                    bf16_t* __restrict__ kT) {
    __shared__ bf16_t tile[64][80];
    const int kt = blockIdx.x * 64;
    const int ct = blockIdx.y * 64;
    const int b  = blockIdx.z;
    const int t = threadIdx.x;
    {
        int kl = t >> 2, cl = (t & 3) * 16;
        const bf16_t* src = kb + ((size_t)(kt + kl) * 4 + b) * 512 + ct + cl;
        *(uint4*)&tile[kl][cl]     = *(const uint4*)src;
        *(uint4*)&tile[kl][cl + 8] = *(const uint4*)(src + 8);
    }
    __syncthreads();
    {
        int cl2 = t >> 2, ks = (t & 3) * 16;
        __attribute__((aligned(16))) bf16_t vals[16];
#pragma unroll
        for (int j = 0; j < 16; j++) vals[j] = tile[ks + j][cl2];
        bf16_t* dst = kT + ((size_t)b * 512 + ct + cl2) * VSTR + kt + ks;
        *(uint4*)dst       = *(const uint4*)&vals[0];
        *(uint4*)(dst + 8) = *(const uint4*)&vals[8];
    }
}

// ======== attn helpers: statically-indexed load groups (rule #20) ========
__device__ __forceinline__ void qk_issue(const bf16_t* kb_base, int us, int g,
                                         int row16, bf16x8 (&b0)[8], bf16x8 (&b1)[8]) {
#pragma unroll
    for (int j = 0; j < 8; ++j) {
        int key = us + (g * 8 + j) * 16 + row16;
        int key_eff = key > 4095 ? 4095 : key;
        const bf16_t* kr = kb_base + (size_t)key_eff * KSTR;
        b0[j] = *(const bf16x8*)kr;
        b1[j] = *(const bf16x8*)(kr + 32);
    }
}

__device__ __forceinline__ void qk_compute(int g, bf16x8 (&b0)[8], bf16x8 (&b1)[8],
        const bf16x8 aq0, const bf16x8 aq1, float (&l)[4], bf16_t* PsH,
        int row16, int quad, const int (&sq)[4], const int (&eq)[4], int us) {
    __builtin_amdgcn_s_setprio(1);
#pragma unroll
    for (int j = 0; j < 8; ++j) {
        int it = g * 8 + j;
        f32x4 acc = {};
        acc = __builtin_amdgcn_mfma_f32_16x16x32_bf16(aq0, b0[j], acc, 0, 0, 0);
        acc = __builtin_amdgcn_mfma_f32_16x16x32_bf16(aq1, b1[j], acc, 0, 0, 0);
        int key = us + it * 16 + row16;
#pragma unroll
        for (int r = 0; r < 4; r++) {
            int ql = quad * 4 + r;
            bool valid = (key >= sq[r]) && (key < eq[r]);
            float p = valid ? __expf(0.125f * acc[r]) : 0.0f;
            l[r] += p;
            if (ql < 8) PsH[ql * 904 + it * 16 + row16] = __float2bfloat16(p);
        }
    }
    __builtin_amdgcn_s_setprio(0);
}

__device__ __forceinline__ void pv_issue(const bf16_t* vbase, int g, int row16, int quad,
                                         bf16x8 (&vb)[4][4]) {
#pragma unroll
    for (int j = 0; j < 4; ++j) {
        int it = g * 4 + j;
#pragma unroll
        for (int nt = 0; nt < 4; ++nt)
            vb[j][nt] = *(const bf16x8*)(vbase + (size_t)(nt * 16 + row16) * VSTR
                                         + it * 32 + quad * 8);
    }
}

__device__ __forceinline__ void pv_compute(int g, bf16x8 (&vb)[4][4], const bf16_t* PsH,
        const bf16_t* Zrow, int row16, int quad, f32x4 (&o)[4]) {
    __builtin_amdgcn_s_setprio(1);
#pragma unroll
    for (int j = 0; j < 4; ++j) {
        int it = g * 4 + j;
        const bf16_t* ap_src = (row16 < 8) ? &PsH[row16 * 904 + it * 32 + quad * 8]
                                           : &Zrow[0];
        bf16x8 ap = *(const bf16x8*)ap_src;
#pragma unroll
        for (int nt = 0; nt < 4; ++nt)
            o[nt] = __builtin_amdgcn_mfma_f32_16x16x32_bf16(ap, vb[j][nt], o[nt], 0, 0, 0);
    }
    __builtin_amdgcn_s_setprio(0);
}

// ---------- MFMA flash attention v8 (proven 51us): 2-deep pipeline + setprio ----------
__global__ __launch_bounds__(512, 1) void attn_mfma(
        const bf16_t* __restrict__ qb,   // [2048,512] rows (q*4+b)
        const bf16_t* __restrict__ kb,   // [4096][KSTR] key-padded
        const bf16_t* __restrict__ vT,   // [4][512][VSTR]
        bf16_t* __restrict__ ctx,        // [2048,512]
        float* __restrict__ attn_out) {  // [4][512][4096], written in full here
    extern __shared__ char smem[];
    bf16_t* Ps   = (bf16_t*)smem;                         // [8 heads][8 q][904]
    bf16_t* Qs   = (bf16_t*)(smem + 115712);              // [8 q][520]
    bf16_t* Zrow = (bf16_t*)(smem + 115712 + 8320);       // [904]
    float*  Ls   = (float*)(smem + 115712 + 8320 + 1808); // [8 heads][8 q] 1/l

    const int blk = blockIdx.x;
    const int b  = (blk & 7) >> 1;                 // batch locked to XCD pair
    const int qt = ((blk >> 3) << 1) | (blk & 1);  // 0..63
    const int q0 = qt * 8;
    const int tid = threadIdx.x;
    const int lane = tid & 63;
    const int h = tid >> 6;          // wave = head 0..7
    const int hoffg = h * HEADDIM;
    const int row16 = lane & 15;
    const int quad = lane >> 4;

    int us; { int s = q0 * 8, e = s + 827; if (e > 4095) s = 3268; us = s; }
    int sq[4], eq[4];
#pragma unroll
    for (int r = 0; r < 4; r++) {
        int ql = quad * 4 + r;
        if (ql < 8) {
            int s = (q0 + ql) * 8, e = s + 827;
            if (e > 4095) { s = 3268; e = 4096; }
            sq[r] = s; eq[r] = e;
        } else { sq[r] = 0; eq[r] = 0; }
    }

    {   // stage Q: 8 rows x 512 cols (16B per thread)
        int r = tid >> 6, coff = (tid & 63) * 8;
        *(uint4*)&Qs[r * 520 + coff] =
            *(const uint4*)(qb + ((size_t)(q0 + r) * 4 + b) * 512 + coff);
        if (tid < 113) { uint4 z = {0, 0, 0, 0}; *(uint4*)&Zrow[tid * 8] = z; }
    }
    __syncthreads();

    const bf16_t* q0p = (row16 < 8) ? &Qs[row16 * 520 + hoffg + quad * 8] : &Zrow[0];
    const bf16_t* q1p = (row16 < 8) ? &Qs[row16 * 520 + hoffg + 32 + quad * 8] : &Zrow[8];
    const bf16x8 aq0 = *(const bf16x8*)q0p;
    const bf16x8 aq1 = *(const bf16x8*)q1p;

    bf16_t* PsH = Ps + h * 8 * 904;
    const bf16_t* kb_base = kb + b * 512 + hoffg + quad * 8;

    // ---- QK: 7 groups of 8, 2-deep ping-pong register pipeline ----
    bf16x8 ka0[8], ka1[8], kc0[8], kc1[8];
    float l[4] = {0.f, 0.f, 0.f, 0.f};
    qk_issue(kb_base, us, 0, row16, ka0, ka1);
    for (int gg = 0; gg < 3; ++gg) {
        qk_issue(kb_base, us, 2 * gg + 1, row16, kc0, kc1);
        qk_compute(2 * gg, ka0, ka1, aq0, aq1, l, PsH, row16, quad, sq, eq, us);
        qk_issue(kb_base, us, 2 * gg + 2, row16, ka0, ka1);
        qk_compute(2 * gg + 1, kc0, kc1, aq0, aq1, l, PsH, row16, quad, sq, eq, us);
    }
    // PV group-0 loads issue before the final QK compute + the shuffle reduce
    bf16x8 va[4][4], vb_[4][4];
    const bf16_t* vbase = vT + (size_t)(b * 512 + hoffg) * VSTR + us;
    pv_issue(vbase, 0, row16, quad, va);
    qk_compute(6, ka0, ka1, aq0, aq1, l, PsH, row16, quad, sq, eq, us);

#pragma unroll
    for (int off = 1; off < 16; off <<= 1) {
#pragma unroll
        for (int r = 0; r < 4; r++) l[r] += __shfl_xor(l[r], off, 64);
    }
    float linv[4];
#pragma unroll
    for (int r = 0; r < 4; r++) linv[r] = 1.0f / l[r];
    if (row16 == 0) {
#pragma unroll
        for (int r = 0; r < 4; r++) {
            int ql = quad * 4 + r;
            if (ql < 8) Ls[h * 8 + ql] = linv[r];
        }
    }

    // ---- PV: 7 groups of 4, 2-deep ping-pong (no barrier: own-head Ps) ----
    f32x4 o[4] = {};
    for (int gg = 0; gg < 3; ++gg) {
        pv_issue(vbase, 2 * gg + 1, row16, quad, vb_);
        pv_compute(2 * gg, va, PsH, Zrow, row16, quad, o);
        pv_issue(vbase, 2 * gg + 2, row16, quad, va);
        pv_compute(2 * gg + 1, vb_, PsH, Zrow, row16, quad, o);
    }
    pv_compute(6, va, PsH, Zrow, row16, quad, o);

    __syncthreads();   // all heads' Ps + Ls final -> mean may read

    // ---- attn_out head-mean: full-row stores (zeros outside window) ----
    {
        int qq = h;                    // wave qq owns q-row q0+qq entirely
        float ls[8];
#pragma unroll
        for (int hh = 0; hh < 8; ++hh) ls[hh] = 0.125f * Ls[hh * 8 + qq];
        float* rowp = attn_out + ((size_t)b * LQ + q0 + qq) * LK;
        const bf16_t* ps = Ps + qq * 904;
        for (int it = 0; it < 16; ++it) {
            int c4 = (it * 64 + lane) * 4;          // first col of this float4
            float4 v = {0.f, 0.f, 0.f, 0.f};
            int off = c4 - us;                      // Ps col of element 0
            if (off >= -3 && off < 896) {
#pragma unroll
                for (int e = 0; e < 4; ++e) {
                    int pc = off + e;
                    float s = 0.f;
                    if (pc >= 0 && pc < 896) {
#pragma unroll
                        for (int hh = 0; hh < 8; ++hh)
                            s += ls[hh] * tofl(ps[hh * 8 * 904 + pc]);
                    }
                    (&v.x)[e] = s;
                }
            }
            *(float4*)(rowp + c4) = v;
        }
    }

    // ---- ctx write (own head, no cross-wave combine) ----
#pragma unroll
    for (int nt = 0; nt < 4; nt++) {
#pragma unroll
        for (int r = 0; r < 4; r++) {
            int ql = quad * 4 + r;
            if (ql < 8) {
                ctx[((size_t)(q0 + ql) * 4 + b) * 512 + hoffg + nt * 16 + row16] =
                    __float2bfloat16(o[nt][r] * linv[r]);
            }
        }
    }
}

extern "C" void kernel_launch(void* const* d_in, const int* in_sizes, int n_in,
                              void* d_out, int out_size, void* d_ws, size_t ws_size,
                              hipStream_t stream) {
    const float* tgt    = (const float*)d_in[0];
    const float* memory = (const float*)d_in[1];
    const float* Wq = (const float*)d_in[2];
    const float* bq = (const float*)d_in[3];
    const float* Wk = (const float*)d_in[4];
    const float* bk = (const float*)d_in[5];
    const float* Wv = (const float*)d_in[6];
    const float* bv = (const float*)d_in[7];
    const float* Wo = (const float*)d_in[8];
    const float* bo = (const float*)d_in[9];
    const float* W1 = (const float*)d_in[10];
    const float* b1 = (const float*)d_in[11];
    const float* W2 = (const float*)d_in[12];
    const float* b2 = (const float*)d_in[13];
    const float* ln1w = (const float*)d_in[14];
    const float* ln1b = (const float*)d_in[15];
    const float* ln2w = (const float*)d_in[16];
    const float* ln2b = (const float*)d_in[17];
    const float* ln3w = (const float*)d_in[18];
    const float* ln3b = (const float*)d_in[19];
    const float* ln4w = (const float*)d_in[20];
    const float* ln4b = (const float*)d_in[21];

    const size_t M1 = (size_t)LQ * BATCH;      // 2048
    const size_t M2 = (size_t)LK * BATCH;      // 16384
    const size_t SZ1 = M1 * DMODEL;

    // ---- workspace map (64 MiB, lifetime-aliased; padded K/vT) ----
    char* wsb = (char*)d_ws;
    const size_t MB = 1 << 20;
    bf16_t* m_buf   = (bf16_t*)(wsb + 0 * MB);   // [2->5], 16MB
    bf16_t* vT_buf  = (bf16_t*)(wsb + 0 * MB);   // [6->7], 16.13MB (m dead)
    bf16_t* h_buf   = (bf16_t*)(wsb + 0 * MB);   // [10->11], 8MB (vT dead)
    bf16_t* k_buf   = (bf16_t*)(wsb + 17 * MB);  // [4->7], 16.25MB padded
    float*  xres    = (float*)(wsb + 17 * MB);   // [8->9], 4MB (k dead)
    float*  xln_f   = (float*)(wsb + 21 * MB);   // [9->11], 4MB
    float*  x2_buf  = (float*)(wsb + 25 * MB);   // [11->12], 4MB
    bf16_t* W2_bf   = (bf16_t*)(wsb + 34 * MB);  // [6.5->11], 2MB (v region head, v dead)
    bf16_t* v_buf   = (bf16_t*)(wsb + 34 * MB);  // [5->6], 16MB
    bf16_t* t_bf    = (bf16_t*)(wsb + 50 * MB);  // [2->3], 2MB
    bf16_t* xln_bf  = (bf16_t*)(wsb + 50 * MB);  // [9->10], 2MB (t_bf dead)
    float*  t_f32   = (float*)(wsb + 52 * MB);   // [2->8], 4MB
    bf16_t* q_bf    = (bf16_t*)(wsb + 56 * MB);  // [3->7], 2MB
    bf16_t* ctx_buf = (bf16_t*)(wsb + 58 * MB);  // [7->8], 2MB
    bf16_t* wqkvo   = (bf16_t*)(wsb + 60 * MB);  // [1->8], 2MB
    bf16_t* W1_bf   = (bf16_t*)(wsb + 62 * MB);  // [1->10], 2MB

    bf16_t* Wq_bf = wqkvo;
    bf16_t* Wk_bf = wqkvo + 262144;
    bf16_t* Wv_bf = wqkvo + 2 * 262144;
    bf16_t* Wo_bf = wqkvo + 3 * 262144;

    float* out_x    = (float*)d_out;
    float* out_attn = out_x + SZ1;

    // 1. LN1 (dual) + LN2 + weight conversions, single leading launch
    ln12_prep_kernel<<<dim3(M1 + M2 + 2048), dim3(256), 0, stream>>>(
        tgt, memory, ln1w, ln1b, ln2w, ln2b, t_bf, t_f32, m_buf,
        Wq, Wk, Wv, Wo, W1, wqkvo, W1_bf);

    // 2. Q projection (64x64 tiles: 256 blocks; operands L2-resident)
    gemm64<bf16_t, false, false><<<dim3(8, 32), dim3(256), 0, stream>>>(
        t_bf, Wq_bf, bq, nullptr, q_bf, M1, DMODEL, DMODEL);

    // 3. K+V projections: 128^2 tiles (proven), one z-fused launch
    gemm128_kv<<<dim3(4, 128, 2), dim3(256), 0, stream>>>(
        m_buf, Wk_bf, Wv_bf, bk, bv, k_buf, v_buf, M2, DMODEL, DMODEL);

    // 4. V transpose to padded [b][d][VSTR] (m_buf dead -> vT region)
    transpose_kv<<<dim3(64, 8, 4), dim3(256), 0, stream>>>(v_buf, vT_buf);

    // 5. W2 conversion into dead v_buf head
    conv_w2<<<dim3(1024), dim3(256), 0, stream>>>(W2, W2_bf);

    // 6. attention: 256 blocks x 8 waves (= 8 heads), 126KB dynamic LDS
    const int attn_lds = 115712 + 8320 + 1808 + 256;   // 126096 B
    hipFuncSetAttribute((const void*)attn_mfma,
                        hipFuncAttributeMaxDynamicSharedMemorySize, attn_lds);
    attn_mfma<<<dim3(256), dim3(512), attn_lds, stream>>>(
        q_bf, k_buf, vT_buf, ctx_buf, out_attn);

    // 7. out proj + residual(t) -> xres (64x64 tiles, 256 blocks)
    gemm64<float, false, true><<<dim3(8, 32), dim3(256), 0, stream>>>(
        ctx_buf, Wo_bf, bo, t_f32, xres, M1, DMODEL, DMODEL);

    // 8. LN3 (dual)
    ln_kernel<bf16_t, true><<<dim3(M1), dim3(256), 0, stream>>>(xres, ln3w, ln3b, xln_bf, xln_f);

    // 9. FF1 (relu): 64x64 tiles, 1024 blocks (A,B L2-resident)
    gemm64<bf16_t, true, false><<<dim3(32, 32), dim3(256), 0, stream>>>(
        xln_bf, W1_bf, b1, nullptr, h_buf, M1, DFF, DMODEL);

    // 10. FF2 + residual(xln) (64x64 tiles, 256 blocks)
    gemm64<float, false, true><<<dim3(8, 32), dim3(256), 0, stream>>>(
        h_buf, W2_bf, b2, xln_f, x2_buf, M1, DMODEL, DFF);

    // 11. LN4 -> fp32 out
    ln_kernel<float, false><<<dim3(M1), dim3(256), 0, stream>>>(x2_buf, ln4w, ln4b, out_x, nullptr);
}

// Round 12
// 279.605 us; speedup vs baseline: 1.0915x; 1.0283x over previous
//
#include <hip/hip_runtime.h>
#include <hip/hip_bf16.h>

typedef __hip_bfloat16 bf16_t;
typedef __bf16 bf16x8 __attribute__((ext_vector_type(8)));
typedef float f32x4 __attribute__((ext_vector_type(4)));

#define LQ 512
#define LK 4096
#define BATCH 4
#define DMODEL 512
#define NHEAD 8
#define HEADDIM 64
#define DFF 2048
#define LN_EPS 1e-5f

// padded strides: 64B-aligned rows (no line straddle), rotate 64B/row mod 4KB
#define KSTR 2080   // elements per key in k_buf: 4160B/key
#define VSTR 4128   // elements per (b,c) row in vT: 8256B/row

__device__ inline float tofl(float x) { return x; }
__device__ inline float tofl(bf16_t x) { return __bfloat162float(x); }
__device__ inline void stfl(float* p, float v) { *p = v; }
__device__ inline void stfl(bf16_t* p, float v) { *p = __float2bfloat16(v); }

// async global->LDS 16B copy: LDS dest = wave-uniform base + lane*16
__device__ __forceinline__ void gld_lds16(const bf16_t* g, void* lds_base) {
    __builtin_amdgcn_global_load_lds(
        (const __attribute__((address_space(1))) uint32_t*)g,
        (__attribute__((address_space(3))) uint32_t*)lds_base, 16, 0, 0);
}

// ---------- LayerNorm (generic, templated) ----------
template <typename TOUT, bool DUAL>
__global__ void ln_kernel(const float* __restrict__ in, const float* __restrict__ w,
                          const float* __restrict__ b, TOUT* __restrict__ out1,
                          float* __restrict__ out2) {
    __shared__ float red[256];
    const int row = blockIdx.x;
    const int tid = threadIdx.x;
    const float* x = in + (size_t)row * DMODEL;
    float v0 = x[tid];
    float v1 = x[tid + 256];

    red[tid] = v0 + v1;
    __syncthreads();
    for (int s = 128; s > 0; s >>= 1) { if (tid < s) red[tid] += red[tid + s]; __syncthreads(); }
    float mu = red[0] * (1.0f / DMODEL);
    __syncthreads();

    float d0 = v0 - mu, d1 = v1 - mu;
    red[tid] = d0 * d0 + d1 * d1;
    __syncthreads();
    for (int s = 128; s > 0; s >>= 1) { if (tid < s) red[tid] += red[tid + s]; __syncthreads(); }
    float inv = rsqrtf(red[0] * (1.0f / DMODEL) + LN_EPS);

    float r0 = d0 * inv * w[tid] + b[tid];
    float r1 = d1 * inv * w[tid + 256] + b[tid + 256];
    TOUT* o = out1 + (size_t)row * DMODEL;
    stfl(&o[tid], r0);
    stfl(&o[tid + 256], r1);
    if (DUAL) {
        float* o2 = out2 + (size_t)row * DMODEL;
        o2[tid] = r0;
        o2[tid + 256] = r1;
    }
}

// ---------- fused LN1 + LN2 + weight-prep (one leading launch) ----------
// blocks [0,18432): LN rows; [18432,20480): Wq/Wk/Wv/Wo+W1 bf16 conversion.
__global__ void ln12_prep_kernel(const float* __restrict__ tgt, const float* __restrict__ memory,
                                 const float* __restrict__ w1, const float* __restrict__ b1,
                                 const float* __restrict__ w2, const float* __restrict__ b2,
                                 bf16_t* __restrict__ t_bf, float* __restrict__ t_f32,
                                 bf16_t* __restrict__ m_buf,
                                 const float* __restrict__ s0, const float* __restrict__ s1,
                                 const float* __restrict__ s2, const float* __restrict__ s3,
                                 const float* __restrict__ s4,
                                 bf16_t* __restrict__ wqkvo, bf16_t* __restrict__ w1bf) {
    const int row = blockIdx.x;
    const int tid = threadIdx.x;
    if (row >= 18432) {
        // ---- prep path ----
        int t = (row - 18432) * 256 + tid;
        int which = t >> 16;            // 0..7, 262144 elements each
        int idx = (t & 65535) * 4;
        const float* s; bf16_t* d;
        if (which < 4) {
            s = (which == 0 ? s0 : which == 1 ? s1 : which == 2 ? s2 : s3);
            d = wqkvo + (size_t)which * 262144;
        } else {
            s = s4 + (size_t)(which - 4) * 262144;
            d = w1bf + (size_t)(which - 4) * 262144;
        }
        float4 v = *(const float4*)(s + idx);
        d[idx + 0] = __float2bfloat16(v.x);
        d[idx + 1] = __float2bfloat16(v.y);
        d[idx + 2] = __float2bfloat16(v.z);
        d[idx + 3] = __float2bfloat16(v.w);
        return;
    }
    __shared__ float red[256];
    const float* in; const float* w; const float* b;
    bf16_t* o1; float* o2; bool dual;
    if (row < 2048) {
        in = tgt + (size_t)row * DMODEL; w = w1; b = b1;
        o1 = t_bf + (size_t)row * DMODEL; o2 = t_f32 + (size_t)row * DMODEL; dual = true;
    } else {
        int r2 = row - 2048;
        in = memory + (size_t)r2 * DMODEL; w = w2; b = b2;
        o1 = m_buf + (size_t)r2 * DMODEL; o2 = nullptr; dual = false;
    }
    float v0 = in[tid];
    float v1 = in[tid + 256];
    red[tid] = v0 + v1;
    __syncthreads();
    for (int s = 128; s > 0; s >>= 1) { if (tid < s) red[tid] += red[tid + s]; __syncthreads(); }
    float mu = red[0] * (1.0f / DMODEL);
    __syncthreads();
    float d0 = v0 - mu, d1 = v1 - mu;
    red[tid] = d0 * d0 + d1 * d1;
    __syncthreads();
    for (int s = 128; s > 0; s >>= 1) { if (tid < s) red[tid] += red[tid + s]; __syncthreads(); }
    float inv = rsqrtf(red[0] * (1.0f / DMODEL) + LN_EPS);
    float r0 = d0 * inv * w[tid] + b[tid];
    float r1 = d1 * inv * w[tid + 256] + b[tid + 256];
    o1[tid] = __float2bfloat16(r0);
    o1[tid + 256] = __float2bfloat16(r1);
    if (dual) {
        o2[tid] = r0;
        o2[tid + 256] = r1;
    }
}

// ---------- MFMA GEMM, 64x64 tile: for GEMMs with cache-resident operands ----------
// R8/R9 lesson: grid-fill wins when A,B fit L2 (Q/Wo/FF1/FF2); for 16MB-A
// GEMMs (K/V) the extra A re-reads cost more than the occupancy gain.
template <typename TC, bool RELU, bool RESID>
__global__ __launch_bounds__(256) void gemm64(
        const bf16_t* __restrict__ A, const bf16_t* __restrict__ B,
        const float* __restrict__ bias, const float* __restrict__ resid,
        TC* __restrict__ C, int M, int N, int K) {
    __shared__ uint4 As4[512];           // 64 rows x 8 chunks
    __shared__ uint4 Bs4[512];

    const int tid = threadIdx.x;
    const int lane = tid & 63;
    const int wave = tid >> 6;
    const int row16 = lane & 15;
    const int quad = lane >> 4;
    const int n0 = blockIdx.x * 64;
    const int m0 = blockIdx.y * 64;

    const int wy = wave >> 1;            // 0/1
    const int wx = wave & 1;             // 0/1
    const int m_base = wy * 32;
    const int n_base = wx * 32;

    const int rr = lane >> 3;
    const int kc = (lane & 7) ^ rr;
    const int kx = row16 & 7;

    const bf16_t* AsE = (const bf16_t*)As4;
    const bf16_t* BsE = (const bf16_t*)Bs4;

    f32x4 acc[2][2] = {};

    for (int k0 = 0; k0 < K; k0 += 64) {
#pragma unroll
        for (int it = 0; it < 2; it++) {
            int issue = it * 4 + wave;
            int r = issue * 8 + rr;
            gld_lds16(A + (size_t)(m0 + r) * K + k0 + kc * 8, &As4[issue * 64]);
        }
#pragma unroll
        for (int it = 0; it < 2; it++) {
            int issue = it * 4 + wave;
            int r = issue * 8 + rr;
            gld_lds16(B + (size_t)(n0 + r) * K + k0 + kc * 8, &Bs4[issue * 64]);
        }
        __syncthreads();
#pragma unroll
        for (int s = 0; s < 2; s++) {
            const int kq = s * 4 + quad;
            const int kcs = (kq ^ kx) * 8;
            bf16x8 af[2], bfr[2];
#pragma unroll
            for (int i = 0; i < 2; i++)
                af[i] = *(const bf16x8*)&AsE[(m_base + i * 16 + row16) * 64 + kcs];
#pragma unroll
            for (int j = 0; j < 2; j++)
                bfr[j] = *(const bf16x8*)&BsE[(n_base + j * 16 + row16) * 64 + kcs];
#pragma unroll
            for (int i = 0; i < 2; i++)
#pragma unroll
                for (int j = 0; j < 2; j++)
                    acc[i][j] = __builtin_amdgcn_mfma_f32_16x16x32_bf16(af[i], bfr[j], acc[i][j], 0, 0, 0);
        }
        __syncthreads();
    }

#pragma unroll
    for (int i = 0; i < 2; i++) {
#pragma unroll
        for (int j = 0; j < 2; j++) {
            int col = n0 + n_base + j * 16 + row16;
            float bsv = bias[col];
#pragma unroll
            for (int r = 0; r < 4; r++) {
                int row = m0 + m_base + i * 16 + quad * 4 + r;
                float val = acc[i][j][r] + bsv;
                if (RESID) val += resid[(size_t)row * N + col];
                if (RELU) val = fmaxf(val, 0.0f);
                stfl(&C[(size_t)row * N + col], val);
            }
        }
    }
}

// ---------- fused Q+K+V projections in ONE launch ----------
// R11 post-mortem: each launch boundary costs ~5-10us (38us gain from 2 merges
// where work-accounting said 15). Blocks [0,1024): K/V at 128^2 tiles (proven
// gemm128_kv body; kv=0 K w/ key-padded epilogue, kv=1 V linear). Blocks
// [1024,1280): Q at 64^2 tiles (proven gemm64 body). Block-uniform branch.
__global__ __launch_bounds__(256) void proj_qkv(
        const bf16_t* __restrict__ At, const bf16_t* __restrict__ Am,
        const bf16_t* __restrict__ BQ, const bf16_t* __restrict__ BK,
        const bf16_t* __restrict__ BV, const float* __restrict__ biasq,
        const float* __restrict__ biask, const float* __restrict__ biasv,
        bf16_t* __restrict__ CQ, bf16_t* __restrict__ CK, bf16_t* __restrict__ CV) {
    __shared__ uint4 As4[1024];          // 32KB total; Q path uses first 512
    __shared__ uint4 Bs4[1024];

    const int bid = blockIdx.x;
    const int tid = threadIdx.x;
    const int lane = tid & 63;
    const int wave = tid >> 6;
    const int row16 = lane & 15;
    const int quad = lane >> 4;
    const int rr = lane >> 3;
    const int kc = (lane & 7) ^ rr;
    const int kx = row16 & 7;

    const bf16_t* AsE = (const bf16_t*)As4;
    const bf16_t* BsE = (const bf16_t*)Bs4;

    if (bid < 1024) {
        // ================= K/V path: 128x128 tile, M=16384, K=512 =================
        const bool isV = (bid >> 9) != 0;
        const int within = bid & 511;
        const int n0 = (within & 3) * 128;
        const int m0 = (within >> 2) * 128;
        const bf16_t* B = isV ? BV : BK;
        const float* bias = isV ? biasv : biask;

        const int wy = wave >> 1;
        const int wx = wave & 1;
        const int m_base = wy * 64;
        const int n_base = wx * 64;

        f32x4 acc[4][4] = {};

        for (int k0 = 0; k0 < DMODEL; k0 += 64) {
#pragma unroll
            for (int it = 0; it < 4; it++) {
                int issue = it * 4 + wave;
                int r = issue * 8 + rr;
                gld_lds16(Am + (size_t)(m0 + r) * DMODEL + k0 + kc * 8, &As4[issue * 64]);
            }
#pragma unroll
            for (int it = 0; it < 4; it++) {
                int issue = it * 4 + wave;
                int r = issue * 8 + rr;
                gld_lds16(B + (size_t)(n0 + r) * DMODEL + k0 + kc * 8, &Bs4[issue * 64]);
            }
            __syncthreads();
#pragma unroll
            for (int s = 0; s < 2; s++) {
                const int kq = s * 4 + quad;
                const int kcs = (kq ^ kx) * 8;
                bf16x8 af[4], bfr[4];
#pragma unroll
                for (int i = 0; i < 4; i++)
                    af[i] = *(const bf16x8*)&AsE[(m_base + i * 16 + row16) * 64 + kcs];
#pragma unroll
                for (int j = 0; j < 4; j++)
                    bfr[j] = *(const bf16x8*)&BsE[(n_base + j * 16 + row16) * 64 + kcs];
#pragma unroll
                for (int i = 0; i < 4; i++)
#pragma unroll
                    for (int j = 0; j < 4; j++)
                        acc[i][j] = __builtin_amdgcn_mfma_f32_16x16x32_bf16(af[i], bfr[j], acc[i][j], 0, 0, 0);
            }
            __syncthreads();
        }

#pragma unroll
        for (int i = 0; i < 4; i++) {
#pragma unroll
            for (int j = 0; j < 4; j++) {
                int col = n0 + n_base + j * 16 + row16;
                float bsv = bias[col];
#pragma unroll
                for (int r = 0; r < 4; r++) {
                    int row = m0 + m_base + i * 16 + quad * 4 + r;
                    float val = acc[i][j][r] + bsv;
                    if (isV) {
                        CV[(size_t)row * DMODEL + col] = __float2bfloat16(val);
                    } else {
                        CK[(size_t)(row >> 2) * KSTR + (size_t)(row & 3) * 512 + col] =
                            __float2bfloat16(val);
                    }
                }
            }
        }
    } else {
        // ================= Q path: 64x64 tile, M=2048, K=512 =================
        const int q = bid - 1024;        // 0..255
        const int n0 = (q & 7) * 64;
        const int m0 = (q >> 3) * 64;

        const int wy = wave >> 1;
        const int wx = wave & 1;
        const int m_base = wy * 32;
        const int n_base = wx * 32;

        f32x4 acc[2][2] = {};

        for (int k0 = 0; k0 < DMODEL; k0 += 64) {
#pragma unroll
            for (int it = 0; it < 2; it++) {
                int issue = it * 4 + wave;
                int r = issue * 8 + rr;
                gld_lds16(At + (size_t)(m0 + r) * DMODEL + k0 + kc * 8, &As4[issue * 64]);
            }
#pragma unroll
            for (int it = 0; it < 2; it++) {
                int issue = it * 4 + wave;
                int r = issue * 8 + rr;
                gld_lds16(BQ + (size_t)(n0 + r) * DMODEL + k0 + kc * 8, &Bs4[issue * 64]);
            }
            __syncthreads();
#pragma unroll
            for (int s = 0; s < 2; s++) {
                const int kq = s * 4 + quad;
                const int kcs = (kq ^ kx) * 8;
                bf16x8 af[2], bfr[2];
#pragma unroll
                for (int i = 0; i < 2; i++)
                    af[i] = *(const bf16x8*)&AsE[(m_base + i * 16 + row16) * 64 + kcs];
#pragma unroll
                for (int j = 0; j < 2; j++)
                    bfr[j] = *(const bf16x8*)&BsE[(n_base + j * 16 + row16) * 64 + kcs];
#pragma unroll
                for (int i = 0; i < 2; i++)
#pragma unroll
                    for (int j = 0; j < 2; j++)
                        acc[i][j] = __builtin_amdgcn_mfma_f32_16x16x32_bf16(af[i], bfr[j], acc[i][j], 0, 0, 0);
            }
            __syncthreads();
        }

#pragma unroll
        for (int i = 0; i < 2; i++) {
#pragma unroll
            for (int j = 0; j < 2; j++) {
                int col = n0 + n_base + j * 16 + row16;
                float bsv = biasq[col];
#pragma unroll
                for (int r = 0; r < 4; r++) {
                    int row = m0 + m_base + i * 16 + quad * 4 + r;
                    CQ[(size_t)row * DMODEL + col] = __float2bfloat16(acc[i][j][r] + bsv);
                }
            }
        }
    }
}

// ---------- fused V-transpose + W2 conversion (one launch) ----------
// blocks [0,2048): transpose in[(key*4+b)*512+c] -> out[(b*512+c)*VSTR+key];
// blocks [2048,3072): W2 fp32->bf16 (1M elements).
__global__ __launch_bounds__(256) void post_kv(const bf16_t* __restrict__ kb,
                                               bf16_t* __restrict__ kT,
                                               const float* __restrict__ w2s,
                                               bf16_t* __restrict__ w2d) {
    __shared__ bf16_t tile[64][80];
    const int bid = blockIdx.x;
    const int t = threadIdx.x;
    if (bid >= 2048) {
        int i = ((bid - 2048) * 256 + t) * 4;
        float4 v = *(const float4*)(w2s + i);
        w2d[i + 0] = __float2bfloat16(v.x);
        w2d[i + 1] = __float2bfloat16(v.y);
        w2d[i + 2] = __float2bfloat16(v.z);
        w2d[i + 3] = __float2bfloat16(v.w);
        return;
    }
    const int kt = (bid & 63) * 64;
    const int ct = ((bid >> 6) & 7) * 64;
    const int b  = bid >> 9;
    {
        int kl = t >> 2, cl = (t & 3) * 16;
        const bf16_t* src = kb + ((size_t)(kt + kl) * 4 + b) * 512 + ct + cl;
        *(uint4*)&tile[kl][cl]     = *(const uint4*)src;
        *(uint4*)&tile[kl][cl + 8] = *(const uint4*)(src + 8);
    }
    __syncthreads();
    {
        int cl2 = t >> 2, ks = (t & 3) * 16;
        __attribute__((aligned(16))) bf16_t vals[16];
#pragma unroll
        for (int j = 0; j < 16; j++) vals[j] = tile[ks + j][cl2];
        bf16_t* dst = kT + ((size_t)b * 512 + ct + cl2) * VSTR + kt + ks;
        *(uint4*)dst       = *(const uint4*)&vals[0];
        *(uint4*)(dst + 8) = *(const uint4*)&vals[8];
    }
}

// ======== attn helpers: statically-indexed load groups (rule #20) ========
__device__ __forceinline__ void qk_issue(const bf16_t* kb_base, int us, int g,
                                         int row16, bf16x8 (&b0)[8], bf16x8 (&b1)[8]) {
#pragma unroll
    for (int j = 0; j < 8; ++j) {
        int key = us + (g * 8 + j) * 16 + row16;
        int key_eff = key > 4095 ? 4095 : key;
        const bf16_t* kr = kb_base + (size_t)key_eff * KSTR;
        b0[j] = *(const bf16x8*)kr;
        b1[j] = *(const bf16x8*)(kr + 32);
    }
}

__device__ __forceinline__ void qk_compute(int g, bf16x8 (&b0)[8], bf16x8 (&b1)[8],
        const bf16x8 aq0, const bf16x8 aq1, float (&l)[4], bf16_t* PsH,
        int row16, int quad, const int (&sq)[4], const int (&eq)[4], int us) {
    __builtin_amdgcn_s_setprio(1);
#pragma unroll
    for (int j = 0; j < 8; ++j) {
        int it = g * 8 + j;
        f32x4 acc = {};
        acc = __builtin_amdgcn_mfma_f32_16x16x32_bf16(aq0, b0[j], acc, 0, 0, 0);
        acc = __builtin_amdgcn_mfma_f32_16x16x32_bf16(aq1, b1[j], acc, 0, 0, 0);
        int key = us + it * 16 + row16;
#pragma unroll
        for (int r = 0; r < 4; r++) {
            int ql = quad * 4 + r;
            bool valid = (key >= sq[r]) && (key < eq[r]);
            float p = valid ? __expf(0.125f * acc[r]) : 0.0f;
            l[r] += p;
            if (ql < 8) PsH[ql * 904 + it * 16 + row16] = __float2bfloat16(p);
        }
    }
    __builtin_amdgcn_s_setprio(0);
}

__device__ __forceinline__ void pv_issue(const bf16_t* vbase, int g, int row16, int quad,
                                         bf16x8 (&vb)[4][4]) {
#pragma unroll
    for (int j = 0; j < 4; ++j) {
        int it = g * 4 + j;
#pragma unroll
        for (int nt = 0; nt < 4; ++nt)
            vb[j][nt] = *(const bf16x8*)(vbase + (size_t)(nt * 16 + row16) * VSTR
                                         + it * 32 + quad * 8);
    }
}

__device__ __forceinline__ void pv_compute(int g, bf16x8 (&vb)[4][4], const bf16_t* PsH,
        const bf16_t* Zrow, int row16, int quad, f32x4 (&o)[4]) {
    __builtin_amdgcn_s_setprio(1);
#pragma unroll
    for (int j = 0; j < 4; ++j) {
        int it = g * 4 + j;
        const bf16_t* ap_src = (row16 < 8) ? &PsH[row16 * 904 + it * 32 + quad * 8]
                                           : &Zrow[0];
        bf16x8 ap = *(const bf16x8*)ap_src;
#pragma unroll
        for (int nt = 0; nt < 4; ++nt)
            o[nt] = __builtin_amdgcn_mfma_f32_16x16x32_bf16(ap, vb[j][nt], o[nt], 0, 0, 0);
    }
    __builtin_amdgcn_s_setprio(0);
}

// ---------- MFMA flash attention v8 (proven 51us): 2-deep pipeline + setprio ----------
__global__ __launch_bounds__(512, 1) void attn_mfma(
        const bf16_t* __restrict__ qb,   // [2048,512] rows (q*4+b)
        const bf16_t* __restrict__ kb,   // [4096][KSTR] key-padded
        const bf16_t* __restrict__ vT,   // [4][512][VSTR]
        bf16_t* __restrict__ ctx,        // [2048,512]
        float* __restrict__ attn_out) {  // [4][512][4096], written in full here
    extern __shared__ char smem[];
    bf16_t* Ps   = (bf16_t*)smem;                         // [8 heads][8 q][904]
    bf16_t* Qs   = (bf16_t*)(smem + 115712);              // [8 q][520]
    bf16_t* Zrow = (bf16_t*)(smem + 115712 + 8320);       // [904]
    float*  Ls   = (float*)(smem + 115712 + 8320 + 1808); // [8 heads][8 q] 1/l

    const int blk = blockIdx.x;
    const int b  = (blk & 7) >> 1;                 // batch locked to XCD pair
    const int qt = ((blk >> 3) << 1) | (blk & 1);  // 0..63
    const int q0 = qt * 8;
    const int tid = threadIdx.x;
    const int lane = tid & 63;
    const int h = tid >> 6;          // wave = head 0..7
    const int hoffg = h * HEADDIM;
    const int row16 = lane & 15;
    const int quad = lane >> 4;

    int us; { int s = q0 * 8, e = s + 827; if (e > 4095) s = 3268; us = s; }
    int sq[4], eq[4];
#pragma unroll
    for (int r = 0; r < 4; r++) {
        int ql = quad * 4 + r;
        if (ql < 8) {
            int s = (q0 + ql) * 8, e = s + 827;
            if (e > 4095) { s = 3268; e = 4096; }
            sq[r] = s; eq[r] = e;
        } else { sq[r] = 0; eq[r] = 0; }
    }

    {   // stage Q: 8 rows x 512 cols (16B per thread)
        int r = tid >> 6, coff = (tid & 63) * 8;
        *(uint4*)&Qs[r * 520 + coff] =
            *(const uint4*)(qb + ((size_t)(q0 + r) * 4 + b) * 512 + coff);
        if (tid < 113) { uint4 z = {0, 0, 0, 0}; *(uint4*)&Zrow[tid * 8] = z; }
    }
    __syncthreads();

    const bf16_t* q0p = (row16 < 8) ? &Qs[row16 * 520 + hoffg + quad * 8] : &Zrow[0];
    const bf16_t* q1p = (row16 < 8) ? &Qs[row16 * 520 + hoffg + 32 + quad * 8] : &Zrow[8];
    const bf16x8 aq0 = *(const bf16x8*)q0p;
    const bf16x8 aq1 = *(const bf16x8*)q1p;

    bf16_t* PsH = Ps + h * 8 * 904;
    const bf16_t* kb_base = kb + b * 512 + hoffg + quad * 8;

    // ---- QK: 7 groups of 8, 2-deep ping-pong register pipeline ----
    bf16x8 ka0[8], ka1[8], kc0[8], kc1[8];
    float l[4] = {0.f, 0.f, 0.f, 0.f};
    qk_issue(kb_base, us, 0, row16, ka0, ka1);
    for (int gg = 0; gg < 3; ++gg) {
        qk_issue(kb_base, us, 2 * gg + 1, row16, kc0, kc1);
        qk_compute(2 * gg, ka0, ka1, aq0, aq1, l, PsH, row16, quad, sq, eq, us);
        qk_issue(kb_base, us, 2 * gg + 2, row16, ka0, ka1);
        qk_compute(2 * gg + 1, kc0, kc1, aq0, aq1, l, PsH, row16, quad, sq, eq, us);
    }
    // PV group-0 loads issue before the final QK compute + the shuffle reduce
    bf16x8 va[4][4], vb_[4][4];
    const bf16_t* vbase = vT + (size_t)(b * 512 + hoffg) * VSTR + us;
    pv_issue(vbase, 0, row16, quad, va);
    qk_compute(6, ka0, ka1, aq0, aq1, l, PsH, row16, quad, sq, eq, us);

#pragma unroll
    for (int off = 1; off < 16; off <<= 1) {
#pragma unroll
        for (int r = 0; r < 4; r++) l[r] += __shfl_xor(l[r], off, 64);
    }
    float linv[4];
#pragma unroll
    for (int r = 0; r < 4; r++) linv[r] = 1.0f / l[r];
    if (row16 == 0) {
#pragma unroll
        for (int r = 0; r < 4; r++) {
            int ql = quad * 4 + r;
            if (ql < 8) Ls[h * 8 + ql] = linv[r];
        }
    }

    // ---- PV: 7 groups of 4, 2-deep ping-pong (no barrier: own-head Ps) ----
    f32x4 o[4] = {};
    for (int gg = 0; gg < 3; ++gg) {
        pv_issue(vbase, 2 * gg + 1, row16, quad, vb_);
        pv_compute(2 * gg, va, PsH, Zrow, row16, quad, o);
        pv_issue(vbase, 2 * gg + 2, row16, quad, va);
        pv_compute(2 * gg + 1, vb_, PsH, Zrow, row16, quad, o);
    }
    pv_compute(6, va, PsH, Zrow, row16, quad, o);

    __syncthreads();   // all heads' Ps + Ls final -> mean may read

    // ---- attn_out head-mean: full-row stores (zeros outside window) ----
    {
        int qq = h;                    // wave qq owns q-row q0+qq entirely
        float ls[8];
#pragma unroll
        for (int hh = 0; hh < 8; ++hh) ls[hh] = 0.125f * Ls[hh * 8 + qq];
        float* rowp = attn_out + ((size_t)b * LQ + q0 + qq) * LK;
        const bf16_t* ps = Ps + qq * 904;
        for (int it = 0; it < 16; ++it) {
            int c4 = (it * 64 + lane) * 4;          // first col of this float4
            float4 v = {0.f, 0.f, 0.f, 0.f};
            int off = c4 - us;                      // Ps col of element 0
            if (off >= -3 && off < 896) {
#pragma unroll
                for (int e = 0; e < 4; ++e) {
                    int pc = off + e;
                    float s = 0.f;
                    if (pc >= 0 && pc < 896) {
#pragma unroll
                        for (int hh = 0; hh < 8; ++hh)
                            s += ls[hh] * tofl(ps[hh * 8 * 904 + pc]);
                    }
                    (&v.x)[e] = s;
                }
            }
            *(float4*)(rowp + c4) = v;
        }
    }

    // ---- ctx write (own head, no cross-wave combine) ----
#pragma unroll
    for (int nt = 0; nt < 4; nt++) {
#pragma unroll
        for (int r = 0; r < 4; r++) {
            int ql = quad * 4 + r;
            if (ql < 8) {
                ctx[((size_t)(q0 + ql) * 4 + b) * 512 + hoffg + nt * 16 + row16] =
                    __float2bfloat16(o[nt][r] * linv[r]);
            }
        }
    }
}

extern "C" void kernel_launch(void* const* d_in, const int* in_sizes, int n_in,
                              void* d_out, int out_size, void* d_ws, size_t ws_size,
                              hipStream_t stream) {
    const float* tgt    = (const float*)d_in[0];
    const float* memory = (const float*)d_in[1];
    const float* Wq = (const float*)d_in[2];
    const float* bq = (const float*)d_in[3];
    const float* Wk = (const float*)d_in[4];
    const float* bk = (const float*)d_in[5];
    const float* Wv = (const float*)d_in[6];
    const float* bv = (const float*)d_in[7];
    const float* Wo = (const float*)d_in[8];
    const float* bo = (const float*)d_in[9];
    const float* W1 = (const float*)d_in[10];
    const float* b1 = (const float*)d_in[11];
    const float* W2 = (const float*)d_in[12];
    const float* b2 = (const float*)d_in[13];
    const float* ln1w = (const float*)d_in[14];
    const float* ln1b = (const float*)d_in[15];
    const float* ln2w = (const float*)d_in[16];
    const float* ln2b = (const float*)d_in[17];
    const float* ln3w = (const float*)d_in[18];
    const float* ln3b = (const float*)d_in[19];
    const float* ln4w = (const float*)d_in[20];
    const float* ln4b = (const float*)d_in[21];

    const size_t M1 = (size_t)LQ * BATCH;      // 2048
    const size_t M2 = (size_t)LK * BATCH;      // 16384
    const size_t SZ1 = M1 * DMODEL;

    // ---- workspace map (64 MiB, lifetime-aliased; padded K/vT) ----
    char* wsb = (char*)d_ws;
    const size_t MB = 1 << 20;
    bf16_t* m_buf   = (bf16_t*)(wsb + 0 * MB);   // [1->3], 16MB
    bf16_t* vT_buf  = (bf16_t*)(wsb + 0 * MB);   // [3->6], 16.13MB (m dead)
    bf16_t* h_buf   = (bf16_t*)(wsb + 0 * MB);   // [9->10], 8MB (vT dead)
    bf16_t* k_buf   = (bf16_t*)(wsb + 17 * MB);  // [2->6], 16.25MB padded
    float*  xres    = (float*)(wsb + 17 * MB);   // [7->8], 4MB (k dead)
    float*  xln_f   = (float*)(wsb + 21 * MB);   // [8->10], 4MB
    float*  x2_buf  = (float*)(wsb + 25 * MB);   // [10->11], 4MB
    bf16_t* W2_bf   = (bf16_t*)(wsb + 34 * MB);  // [3->10], 2MB (v region head, v dead)
    bf16_t* v_buf   = (bf16_t*)(wsb + 34 * MB);  // [2->3], 16MB
    bf16_t* t_bf    = (bf16_t*)(wsb + 50 * MB);  // [1->2], 2MB
    bf16_t* xln_bf  = (bf16_t*)(wsb + 50 * MB);  // [8->9], 2MB (t_bf dead)
    float*  t_f32   = (float*)(wsb + 52 * MB);   // [1->7], 4MB
    bf16_t* q_bf    = (bf16_t*)(wsb + 56 * MB);  // [2->6], 2MB
    bf16_t* ctx_buf = (bf16_t*)(wsb + 58 * MB);  // [6->7], 2MB
    bf16_t* wqkvo   = (bf16_t*)(wsb + 60 * MB);  // [1->7], 2MB
    bf16_t* W1_bf   = (bf16_t*)(wsb + 62 * MB);  // [1->9], 2MB

    bf16_t* Wq_bf = wqkvo;
    bf16_t* Wk_bf = wqkvo + 262144;
    bf16_t* Wv_bf = wqkvo + 2 * 262144;
    bf16_t* Wo_bf = wqkvo + 3 * 262144;

    float* out_x    = (float*)d_out;
    float* out_attn = out_x + SZ1;

    // 1. LN1 (dual) + LN2 + weight conversions, single leading launch
    ln12_prep_kernel<<<dim3(M1 + M2 + 2048), dim3(256), 0, stream>>>(
        tgt, memory, ln1w, ln1b, ln2w, ln2b, t_bf, t_f32, m_buf,
        Wq, Wk, Wv, Wo, W1, wqkvo, W1_bf);

    // 2. Q + K + V projections in ONE launch (1280 blocks)
    proj_qkv<<<dim3(1280), dim3(256), 0, stream>>>(
        t_bf, m_buf, Wq_bf, Wk_bf, Wv_bf, bq, bk, bv, q_bf, k_buf, v_buf);

    // 3. V transpose + W2 conversion in ONE launch (3072 blocks)
    post_kv<<<dim3(3072), dim3(256), 0, stream>>>(v_buf, vT_buf, W2, W2_bf);

    // 4. attention: 256 blocks x 8 waves (= 8 heads), 126KB dynamic LDS
    const int attn_lds = 115712 + 8320 + 1808 + 256;   // 126096 B
    hipFuncSetAttribute((const void*)attn_mfma,
                        hipFuncAttributeMaxDynamicSharedMemorySize, attn_lds);
    attn_mfma<<<dim3(256), dim3(512), attn_lds, stream>>>(
        q_bf, k_buf, vT_buf, ctx_buf, out_attn);

    // 5. out proj + residual(t) -> xres (64x64 tiles, 256 blocks)
    gemm64<float, false, true><<<dim3(8, 32), dim3(256), 0, stream>>>(
        ctx_buf, Wo_bf, bo, t_f32, xres, M1, DMODEL, DMODEL);

    // 6. LN3 (dual)
    ln_kernel<bf16_t, true><<<dim3(M1), dim3(256), 0, stream>>>(xres, ln3w, ln3b, xln_bf, xln_f);

    // 7. FF1 (relu): 64x64 tiles, 1024 blocks (A,B L2-resident)
    gemm64<bf16_t, true, false><<<dim3(32, 32), dim3(256), 0, stream>>>(
        xln_bf, W1_bf, b1, nullptr, h_buf, M1, DFF, DMODEL);

    // 8. FF2 + residual(xln) (64x64 tiles, 256 blocks)
    gemm64<float, false, true><<<dim3(8, 32), dim3(256), 0, stream>>>(
        h_buf, W2_bf, b2, xln_f, x2_buf, M1, DMODEL, DFF);

    // 9. LN4 -> fp32 out
    ln_kernel<float, false><<<dim3(M1), dim3(256), 0, stream>>>(x2_buf, ln4w, ln4b, out_x, nullptr);
}